// Round 2
// baseline (420.314 us; speedup 1.0000x reference)
//
#include <hip/hip_runtime.h>

#ifndef N_NODES
#define N_NODES 100000
#endif
#define E_EDGES 2000000
#define CIN 16
// HUMAN_EXHALATION_FLOW = 0.0001 * 40000 = 4.0
#define EXH_FLOW 4.0f

// origin_data layout: (N, T=8, 3) f32; last timestep fields at n*24 + {21,22,23}
// = {concentration, people, size}

__global__ void init_nodes_kernel(const float* __restrict__ origin,
                                  float* __restrict__ out,
                                  int* __restrict__ max_ord) {
    int n = blockIdx.x * blockDim.x + threadIdx.x;
    if (n >= N_NODES) return;
    size_t base = (size_t)n * 24;
    float conc   = origin[base + 21];
    float people = origin[base + 22];
    float size   = origin[base + 23];
    out[n] = conc + EXH_FLOW * people / size;
    max_ord[n] = -1;
}

__global__ void edge_pass1_kernel(const float* __restrict__ x,
                                  const float* __restrict__ w,
                                  const float* __restrict__ b,
                                  const int* __restrict__ src,
                                  const int* __restrict__ dst,
                                  float* __restrict__ flow,
                                  int* __restrict__ max_ord) {
    int e = blockIdx.x * blockDim.x + threadIdx.x;
    if (e >= E_EDGES) return;
    const float4* xv = (const float4*)(x + (size_t)e * CIN);
    const float4* wv = (const float4*)w;
    float4 a0 = xv[0], a1 = xv[1], a2 = xv[2], a3 = xv[3];
    float4 w0 = wv[0], w1 = wv[1], w2 = wv[2], w3 = wv[3];
    float acc = a0.x * w0.x + a0.y * w0.y + a0.z * w0.z + a0.w * w0.w
              + a1.x * w1.x + a1.y * w1.y + a1.z * w1.z + a1.w * w1.w
              + a2.x * w2.x + a2.y * w2.y + a2.z * w2.z + a2.w * w2.w
              + a3.x * w3.x + a3.y * w3.y + a3.z * w3.z + a3.w * w3.w;
    float out = acc + b[0];
    flow[e] = out;
    int s = src[e], d = dst[e];
    if (s != d) {
        int os = 2 * e;
        int od = 2 * e + 1;
        // test-and-test-and-set: max_ord is monotonically increasing, so a
        // stale cached read is always <= true max -> skip is safe, and a
        // stale-low read just issues a redundant correct atomic.
        if (max_ord[s] < os) atomicMax(&max_ord[s], os);
        if (max_ord[d] < od) atomicMax(&max_ord[d], od);
    }
}

__global__ void edge_pass2_kernel(const float* __restrict__ origin,
                                  const int* __restrict__ src,
                                  const int* __restrict__ dst,
                                  const float* __restrict__ flow,
                                  const int* __restrict__ max_ord,
                                  float* __restrict__ out) {
    int e = blockIdx.x * blockDim.x + threadIdx.x;
    if (e >= E_EDGES) return;
    int s = src[e], d = dst[e];
    if (s == d) return;
    bool win_s = (max_ord[s] == 2 * e);
    bool win_d = (max_ord[d] == 2 * e + 1);
    if (!win_s && !win_d) return;
    float val = flow[e];
    float conc_s = origin[(size_t)s * 24 + 21];
    if (win_s) {
        float size_s = origin[(size_t)s * 24 + 23];
        // unique winner per node -> single writer, non-atomic RMW is safe
        out[s] += val * conc_s / size_s;
    }
    if (win_d) {
        float size_d = origin[(size_t)d * 24 + 23];
        out[d] += val * conc_s / size_d;
    }
}

extern "C" void kernel_launch(void* const* d_in, const int* in_sizes, int n_in,
                              void* d_out, int out_size, void* d_ws, size_t ws_size,
                              hipStream_t stream) {
    const float* origin = (const float*)d_in[0];   // (N, 8, 3)
    const float* x      = (const float*)d_in[1];   // (E, 1, 16)
    const float* conv_w = (const float*)d_in[2];   // (1, 16, 1, 1)
    const float* conv_b = (const float*)d_in[3];   // (1,)
    const int*   eidx   = (const int*)d_in[4];     // (2, E)
    const int* src = eidx;
    const int* dst = eidx + E_EDGES;

    float* out    = (float*)d_out;        // [0, N): result; [N, N+E): flow
    float* flow   = out + N_NODES;
    int*   max_ord = (int*)d_ws;          // N ints

    const int BLK = 256;
    init_nodes_kernel<<<(N_NODES + BLK - 1) / BLK, BLK, 0, stream>>>(origin, out, max_ord);
    edge_pass1_kernel<<<(E_EDGES + BLK - 1) / BLK, BLK, 0, stream>>>(x, conv_w, conv_b,
                                                                     src, dst, flow, max_ord);
    edge_pass2_kernel<<<(E_EDGES + BLK - 1) / BLK, BLK, 0, stream>>>(origin, src, dst,
                                                                     flow, max_ord, out);
}

// Round 3
// 105.511 us; speedup vs baseline: 3.9836x; 3.9836x over previous
//
#include <hip/hip_runtime.h>

#define N_NODES 100000
#define E_EDGES 2000000
#define SPLIT_E 1800000   // top 10% of edges settle ~98% of nodes
#define CIN 16
#define EXH_FLOW 4.0f     // 0.0001 * 40000

// origin_data layout: (N, T=8, 3) f32; last timestep at n*24 + {21,22,23}
// = {concentration, people, size}

__global__ void init_nodes_kernel(const float* __restrict__ origin,
                                  float* __restrict__ out,
                                  int* __restrict__ max_ord,
                                  float* __restrict__ conc_c,
                                  float* __restrict__ rsize_c) {
    int n = blockIdx.x * blockDim.x + threadIdx.x;
    if (n >= N_NODES) return;
    size_t base = (size_t)n * 24;
    float conc   = origin[base + 21];
    float people = origin[base + 22];
    float size   = origin[base + 23];
    float rs = 1.0f / size;
    out[n] = conc + EXH_FLOW * people * rs;
    conc_c[n]  = conc;
    rsize_c[n] = rs;
    max_ord[n] = -1;
}

__device__ __forceinline__ float edge_dot(const float* __restrict__ x,
                                          const float* __restrict__ w,
                                          float bias, int e) {
    const float4* xv = (const float4*)(x + (size_t)e * CIN);
    const float4* wv = (const float4*)w;
    float4 a0 = xv[0], a1 = xv[1], a2 = xv[2], a3 = xv[3];
    float4 w0 = wv[0], w1 = wv[1], w2 = wv[2], w3 = wv[3];
    return a0.x * w0.x + a0.y * w0.y + a0.z * w0.z + a0.w * w0.w
         + a1.x * w1.x + a1.y * w1.y + a1.z * w1.z + a1.w * w1.w
         + a2.x * w2.x + a2.y * w2.y + a2.z * w2.z + a2.w * w2.w
         + a3.x * w3.x + a3.y * w3.y + a3.z * w3.z + a3.w * w3.w
         + bias;
}

// K2: top chunk — pure atomics (no pre-check: values unsettled here anyway,
// and loads under concurrent atomics thrash the cache — R2 lesson).
__global__ void edge_top_kernel(const float* __restrict__ x,
                                const float* __restrict__ w,
                                const float* __restrict__ b,
                                const int* __restrict__ src,
                                const int* __restrict__ dst,
                                float* __restrict__ flow,
                                int* __restrict__ max_ord) {
    int i = blockIdx.x * blockDim.x + threadIdx.x;
    int e = SPLIT_E + i;
    if (e >= E_EDGES) return;
    flow[e] = edge_dot(x, w, b[0], e);
    int s = src[e], d = dst[e];
    if (s != d) {
        atomicMax(&max_ord[s], 2 * e);
        atomicMax(&max_ord[d], 2 * e + 1);
    }
}

// K3: rest — pre-check against SETTLED maxes (kernel boundary = acquire).
// Orders are monotone in e, so any node touched by a valid top-chunk edge
// has max_ord > every order here -> deterministic skip (~98%). Stale-low
// reads just issue a redundant correct atomic.
__global__ void edge_rest_kernel(const float* __restrict__ x,
                                 const float* __restrict__ w,
                                 const float* __restrict__ b,
                                 const int* __restrict__ src,
                                 const int* __restrict__ dst,
                                 float* __restrict__ flow,
                                 int* __restrict__ max_ord) {
    int e = blockIdx.x * blockDim.x + threadIdx.x;
    if (e >= SPLIT_E) return;
    flow[e] = edge_dot(x, w, b[0], e);
    int s = src[e], d = dst[e];
    if (s != d) {
        int os = 2 * e;
        int od = 2 * e + 1;
        if (max_ord[s] < os) atomicMax(&max_ord[s], os);
        if (max_ord[d] < od) atomicMax(&max_ord[d], od);
    }
}

// K5: per-node finalize — decode winning occurrence, gather its value.
// max_ord[n] only ever written by occurrences AT node n, so the decode is exact.
__global__ void finalize_kernel(const int* __restrict__ src,
                                const float* __restrict__ flow,
                                const int* __restrict__ max_ord,
                                const float* __restrict__ conc_c,
                                const float* __restrict__ rsize_c,
                                float* __restrict__ out) {
    int n = blockIdx.x * blockDim.x + threadIdx.x;
    if (n >= N_NODES) return;
    int o = max_ord[n];
    if (o < 0) return;
    int e = o >> 1;
    float val = flow[e];
    float v;
    if ((o & 1) == 0) {
        // src-side winner: src[e] == n
        v = val * conc_c[n] * rsize_c[n];
    } else {
        // dst-side winner: dst[e] == n
        int s = src[e];
        v = val * conc_c[s] * rsize_c[n];
    }
    out[n] += v;
}

extern "C" void kernel_launch(void* const* d_in, const int* in_sizes, int n_in,
                              void* d_out, int out_size, void* d_ws, size_t ws_size,
                              hipStream_t stream) {
    const float* origin = (const float*)d_in[0];   // (N, 8, 3)
    const float* x      = (const float*)d_in[1];   // (E, 1, 16)
    const float* conv_w = (const float*)d_in[2];   // (1, 16, 1, 1)
    const float* conv_b = (const float*)d_in[3];   // (1,)
    const int*   eidx   = (const int*)d_in[4];     // (2, E)
    const int* src = eidx;
    const int* dst = eidx + E_EDGES;

    float* out  = (float*)d_out;          // [0, N): result; [N, N+E): flow
    float* flow = out + N_NODES;

    int*   max_ord = (int*)d_ws;                      // N ints
    float* conc_c  = (float*)((char*)d_ws + 1 * 400 * 1024);
    float* rsize_c = (float*)((char*)d_ws + 2 * 400 * 1024);

    const int BLK = 256;
    init_nodes_kernel<<<(N_NODES + BLK - 1) / BLK, BLK, 0, stream>>>(
        origin, out, max_ord, conc_c, rsize_c);
    edge_top_kernel<<<((E_EDGES - SPLIT_E) + BLK - 1) / BLK, BLK, 0, stream>>>(
        x, conv_w, conv_b, src, dst, flow, max_ord);
    edge_rest_kernel<<<(SPLIT_E + BLK - 1) / BLK, BLK, 0, stream>>>(
        x, conv_w, conv_b, src, dst, flow, max_ord);
    finalize_kernel<<<(N_NODES + BLK - 1) / BLK, BLK, 0, stream>>>(
        src, flow, max_ord, conc_c, rsize_c, out);
}

// Round 4
// 96.897 us; speedup vs baseline: 4.3377x; 1.0889x over previous
//
#include <hip/hip_runtime.h>

#define N_NODES 100000
#define E_EDGES 2000000
#define SPLIT_E 1800000   // top 10% of edges settle ~98% of nodes
#define CIN 16
#define EXH_FLOW 4.0f     // 0.0001 * 40000

// origin_data layout: (N, T=8, 3) f32; last timestep at n*24 + {21,22,23}
// = {concentration, people, size}

__global__ void init_nodes_kernel(const float* __restrict__ origin,
                                  float* __restrict__ out,
                                  int* __restrict__ max_ord,
                                  float* __restrict__ conc_c,
                                  float* __restrict__ rsize_c) {
    int n = blockIdx.x * blockDim.x + threadIdx.x;
    if (n >= N_NODES) return;
    size_t base = (size_t)n * 24;
    float conc   = origin[base + 21];
    float people = origin[base + 22];
    float size   = origin[base + 23];
    float rs = 1.0f / size;
    out[n] = conc + EXH_FLOW * people * rs;
    conc_c[n]  = conc;
    rsize_c[n] = rs;
    max_ord[n] = -1;
}

// Pure stream: 4 lanes per edge, each lane loads ONE float4 of x
// (consecutive lanes -> consecutive 16B => perfectly coalesced dwordx4),
// dots with its quarter of w, 2x shfl_xor reduce within the lane quartet.
__global__ void flow_kernel(const float4* __restrict__ xv,
                            const float* __restrict__ w,
                            const float* __restrict__ b,
                            float* __restrict__ flow) {
    int tid = blockIdx.x * blockDim.x + threadIdx.x;   // over E*4 = 8M
    if (tid >= E_EDGES * 4) return;
    int q = tid & 3;
    float4 v  = xv[tid];
    float4 wq = ((const float4*)w)[q];   // w = 64B, single cache line, L1 broadcast
    float p = v.x * wq.x + v.y * wq.y + v.z * wq.z + v.w * wq.w;
    p += __shfl_xor(p, 1);
    p += __shfl_xor(p, 2);
    if (q == 0) flow[tid >> 2] = p + b[0];   // 16 lanes/wave store 64B contiguous
}

// Top chunk: pure atomics (values unsettled here; pre-check loads under
// in-flight atomics thrash TCC — R2 lesson). No x access at all.
__global__ void scatter_top_kernel(const int* __restrict__ src,
                                   const int* __restrict__ dst,
                                   int* __restrict__ max_ord) {
    int i = blockIdx.x * blockDim.x + threadIdx.x;
    int e = SPLIT_E + i;
    if (e >= E_EDGES) return;
    int s = src[e], d = dst[e];
    if (s != d) {
        atomicMax(&max_ord[s], 2 * e);
        atomicMax(&max_ord[d], 2 * e + 1);
    }
}

// Rest: pre-check against SETTLED maxes (kernel boundary = acquire).
// Orders are monotone in e -> ~98% deterministic skip. 4 edges/thread via
// int4 loads for memory-level parallelism.
__global__ void scatter_rest_kernel(const int* __restrict__ src,
                                    const int* __restrict__ dst,
                                    int* __restrict__ max_ord) {
    int t = blockIdx.x * blockDim.x + threadIdx.x;
    int e0 = t * 4;
    if (e0 >= SPLIT_E) return;
    int4 s4 = *(const int4*)(src + e0);
    int4 d4 = *(const int4*)(dst + e0);
#define PROC(EE, SS, DD)                                                  \
    if ((SS) != (DD)) {                                                   \
        int os = 2 * (EE), od = os + 1;                                   \
        if (max_ord[SS] < os) atomicMax(&max_ord[SS], os);                \
        if (max_ord[DD] < od) atomicMax(&max_ord[DD], od);                \
    }
    PROC(e0 + 0, s4.x, d4.x)
    PROC(e0 + 1, s4.y, d4.y)
    PROC(e0 + 2, s4.z, d4.z)
    PROC(e0 + 3, s4.w, d4.w)
#undef PROC
}

// Per-node finalize: decode winning occurrence, gather its value.
__global__ void finalize_kernel(const int* __restrict__ src,
                                const float* __restrict__ flow,
                                const int* __restrict__ max_ord,
                                const float* __restrict__ conc_c,
                                const float* __restrict__ rsize_c,
                                float* __restrict__ out) {
    int n = blockIdx.x * blockDim.x + threadIdx.x;
    if (n >= N_NODES) return;
    int o = max_ord[n];
    if (o < 0) return;
    int e = o >> 1;
    float val = flow[e];
    float v;
    if ((o & 1) == 0) {
        v = val * conc_c[n] * rsize_c[n];            // src-side: src[e]==n
    } else {
        int s = src[e];
        v = val * conc_c[s] * rsize_c[n];            // dst-side
    }
    out[n] += v;
}

extern "C" void kernel_launch(void* const* d_in, const int* in_sizes, int n_in,
                              void* d_out, int out_size, void* d_ws, size_t ws_size,
                              hipStream_t stream) {
    const float* origin = (const float*)d_in[0];   // (N, 8, 3)
    const float* x      = (const float*)d_in[1];   // (E, 1, 16)
    const float* conv_w = (const float*)d_in[2];   // (1, 16, 1, 1)
    const float* conv_b = (const float*)d_in[3];   // (1,)
    const int*   eidx   = (const int*)d_in[4];     // (2, E)
    const int* src = eidx;
    const int* dst = eidx + E_EDGES;

    float* out  = (float*)d_out;          // [0, N): result; [N, N+E): flow
    float* flow = out + N_NODES;

    int*   max_ord = (int*)d_ws;                      // N ints
    float* conc_c  = (float*)((char*)d_ws + 1 * 400 * 1024);
    float* rsize_c = (float*)((char*)d_ws + 2 * 400 * 1024);

    const int BLK = 256;
    init_nodes_kernel<<<(N_NODES + BLK - 1) / BLK, BLK, 0, stream>>>(
        origin, out, max_ord, conc_c, rsize_c);
    scatter_top_kernel<<<((E_EDGES - SPLIT_E) + BLK - 1) / BLK, BLK, 0, stream>>>(
        src, dst, max_ord);
    scatter_rest_kernel<<<((SPLIT_E / 4) + BLK - 1) / BLK, BLK, 0, stream>>>(
        src, dst, max_ord);
    flow_kernel<<<((E_EDGES * 4) + BLK - 1) / BLK, BLK, 0, stream>>>(
        (const float4*)x, conv_w, conv_b, flow);
    finalize_kernel<<<(N_NODES + BLK - 1) / BLK, BLK, 0, stream>>>(
        src, flow, max_ord, conc_c, rsize_c, out);
}

// Round 5
// 65.952 us; speedup vs baseline: 6.3730x; 1.4692x over previous
//
#include <hip/hip_runtime.h>

#define N_NODES 100000
#define E_EDGES 2000000
#define SPLIT_E 1800000   // top 10% of edges: 400k touches, P(node untouched) ~ e^-4 ~ 1.8%
#define CIN 16
#define EXH_FLOW 4.0f     // 0.0001 * 40000

// origin_data layout: (N, T=8, 3) f32; last timestep at n*24 + {21,22,23}
// = {concentration, people, size}

__global__ void init_nodes_kernel(const float* __restrict__ origin,
                                  float* __restrict__ out,
                                  int* __restrict__ max_ord,
                                  float* __restrict__ conc_c,
                                  float* __restrict__ rsize_c,
                                  unsigned char* __restrict__ settled) {
    int n = blockIdx.x * blockDim.x + threadIdx.x;
    if (n >= N_NODES) return;
    size_t base = (size_t)n * 24;
    float conc   = origin[base + 21];
    float people = origin[base + 22];
    float size   = origin[base + 23];
    float rs = 1.0f / size;
    out[n] = conc + EXH_FLOW * people * rs;
    conc_c[n]  = conc;
    rsize_c[n] = rs;
    max_ord[n] = -1;
    settled[n] = 0;
}

// Top chunk: pure atomics (values unsettled here — R2 lesson: no prechecks
// against a churning table). Also marks touched nodes in the settled byte-map:
// any node touched here has max_ord >= 2*SPLIT_E > every lower order, so its
// max is FINAL once this kernel completes. Same-value byte-store races benign.
__global__ void scatter_top_kernel(const int* __restrict__ src,
                                   const int* __restrict__ dst,
                                   int* __restrict__ max_ord,
                                   unsigned char* __restrict__ settled) {
    int i = blockIdx.x * blockDim.x + threadIdx.x;
    int e = SPLIT_E + i;
    if (e >= E_EDGES) return;
    int s = src[e], d = dst[e];
    if (s != d) {
        atomicMax(&max_ord[s], 2 * e);
        atomicMax(&max_ord[d], 2 * e + 1);
        settled[s] = 1;
        settled[d] = 1;
    }
}

// Main pass: coalesced x-stream (4 lanes/edge, one float4 each, shfl reduce)
// + scatter via the IMMUTABLE settled map. settled is 100 KB, read-only in
// this kernel -> permanently L2-resident in all XCDs, never invalidated.
// Atomics (~2% of nodes unsettled -> ~70k) hit a different array (max_ord).
// Top-range edges skip automatically: they marked their own endpoints settled.
__global__ void fused_flow_scatter_kernel(const float4* __restrict__ xv,
                                          const float* __restrict__ w,
                                          const float* __restrict__ b,
                                          const int* __restrict__ src,
                                          const int* __restrict__ dst,
                                          const unsigned char* __restrict__ settled,
                                          float* __restrict__ flow,
                                          int* __restrict__ max_ord) {
    int tid = blockIdx.x * blockDim.x + threadIdx.x;   // over E*4 = 8M
    if (tid >= E_EDGES * 4) return;
    int q = tid & 3;
    int e = tid >> 2;
    float4 v  = xv[tid];                 // consecutive lanes -> consecutive 16B
    float4 wq = ((const float4*)w)[q];   // 64B total, L1 broadcast
    float p = v.x * wq.x + v.y * wq.y + v.z * wq.z + v.w * wq.w;
    p += __shfl_xor(p, 1);
    p += __shfl_xor(p, 2);
    if (q == 0) {
        flow[e] = p + b[0];              // 16 lanes/wave, 64B line per wave
        int s = src[e], d = dst[e];      // 16 lanes read one 64B line each
        if (s != d) {
            if (!settled[s]) atomicMax(&max_ord[s], 2 * e);
            if (!settled[d]) atomicMax(&max_ord[d], 2 * e + 1);
        }
    }
}

// Per-node finalize: decode winning occurrence, gather its value.
__global__ void finalize_kernel(const int* __restrict__ src,
                                const float* __restrict__ flow,
                                const int* __restrict__ max_ord,
                                const float* __restrict__ conc_c,
                                const float* __restrict__ rsize_c,
                                float* __restrict__ out) {
    int n = blockIdx.x * blockDim.x + threadIdx.x;
    if (n >= N_NODES) return;
    int o = max_ord[n];
    if (o < 0) return;
    int e = o >> 1;
    float val = flow[e];
    float v;
    if ((o & 1) == 0) {
        v = val * conc_c[n] * rsize_c[n];            // src-side: src[e]==n
    } else {
        int s = src[e];
        v = val * conc_c[s] * rsize_c[n];            // dst-side
    }
    out[n] += v;
}

extern "C" void kernel_launch(void* const* d_in, const int* in_sizes, int n_in,
                              void* d_out, int out_size, void* d_ws, size_t ws_size,
                              hipStream_t stream) {
    const float* origin = (const float*)d_in[0];   // (N, 8, 3)
    const float* x      = (const float*)d_in[1];   // (E, 1, 16)
    const float* conv_w = (const float*)d_in[2];   // (1, 16, 1, 1)
    const float* conv_b = (const float*)d_in[3];   // (1,)
    const int*   eidx   = (const int*)d_in[4];     // (2, E)
    const int* src = eidx;
    const int* dst = eidx + E_EDGES;

    float* out  = (float*)d_out;          // [0, N): result; [N, N+E): flow
    float* flow = out + N_NODES;

    int*           max_ord = (int*)d_ws;                           // 400 KB
    float*         conc_c  = (float*)((char*)d_ws + 1 * 400 * 1024);
    float*         rsize_c = (float*)((char*)d_ws + 2 * 400 * 1024);
    unsigned char* settled = (unsigned char*)((char*)d_ws + 3 * 400 * 1024); // 100 KB

    const int BLK = 256;
    init_nodes_kernel<<<(N_NODES + BLK - 1) / BLK, BLK, 0, stream>>>(
        origin, out, max_ord, conc_c, rsize_c, settled);
    scatter_top_kernel<<<((E_EDGES - SPLIT_E) + BLK - 1) / BLK, BLK, 0, stream>>>(
        src, dst, max_ord, settled);
    fused_flow_scatter_kernel<<<((E_EDGES * 4) + BLK - 1) / BLK, BLK, 0, stream>>>(
        (const float4*)x, conv_w, conv_b, src, dst, settled, flow, max_ord);
    finalize_kernel<<<(N_NODES + BLK - 1) / BLK, BLK, 0, stream>>>(
        src, flow, max_ord, conc_c, rsize_c, out);
}